// Round 6
// baseline (207.331 us; speedup 1.0000x reference)
//
#include <hip/hip_runtime.h>
#include <stdint.h>

// Problem constants (fixed by the reference).
#define VOCAB_P1 100001
#define EMB_DIM  128
#define BATCH    256
#define NNZ_Q    2048
#define NNZ_D    262144

#define NPAD 112        // hidden dim 100 padded to 7 MFMA tiles of 16
#define ROWP 136        // w1t LDS row stride in shorts (128 + 8 pad)
#define NGRP 6251       // ceil(100001 / 16) row-groups
#define ZBLK 256        // zero-role blocks
#define MBLK 1024       // mlp-role blocks
#define NCOPY 4         // colsum copies: 1024 scatter blocks / 4 = 256-deep chains
#define OUT_F4 6400128  // out_size/4 = 25,600,512 floats / 4

typedef __attribute__((ext_vector_type(8))) short  short8;
typedef __attribute__((ext_vector_type(4))) float  float4v;

__device__ __forceinline__ unsigned short f2bf(float f) {
    union { float f; unsigned u; } v; v.f = f;
    unsigned u = v.u;
    u += 0x7fffu + ((u >> 16) & 1u);     // RNE float -> bf16
    return (unsigned short)(u >> 16);
}

__device__ __forceinline__ short8 cvt8(float4 a, float4 b) {
    short8 r;
    r[0] = (short)f2bf(a.x); r[1] = (short)f2bf(a.y);
    r[2] = (short)f2bf(a.z); r[3] = (short)f2bf(a.w);
    r[4] = (short)f2bf(b.x); r[5] = (short)f2bf(b.y);
    r[6] = (short)f2bf(b.z); r[7] = (short)f2bf(b.w);
    return r;
}

// Block-role fused kernel (R4-verified):
//   blocks [0, ZBLK): zero d_out (rel + dmat) and the colsum copies.
//   blocks [ZBLK, ZBLK+MBLK): per-unique-row MLP tdv table.
__global__ __launch_bounds__(256) void zero_mlp_kernel(
    float* __restrict__ d_out_f, float* __restrict__ colsum4,
    const float* __restrict__ emb, const float* __restrict__ W1,
    const float* __restrict__ b1, const float* __restrict__ W2,
    const float* __restrict__ b2, float* __restrict__ tdvtab)
{
    const int tid = threadIdx.x;

    if (blockIdx.x < ZBLK) {
        const float4 z = {0.f, 0.f, 0.f, 0.f};
        float4* dst = (float4*)d_out_f;
        int i0 = blockIdx.x * 256 + tid;
        for (int i = i0; i < OUT_F4; i += ZBLK * 256) dst[i] = z;
        if (i0 < NCOPY * BATCH / 4) ((float4*)colsum4)[i0] = z;
        return;
    }

    __shared__ __align__(16) short w1t[NPAD * ROWP];   // 30.5 KB
    __shared__ float b1s[NPAD];
    __shared__ float w2s[NPAD];

    int* w1i = (int*)w1t;
    for (int i = tid; i < NPAD * ROWP / 2; i += 256) w1i[i] = 0;
    __syncthreads();
    for (int f = tid; f < EMB_DIM * 100; f += 256) {
        int k = f / 100, j = f - k * 100;
        w1t[j * ROWP + k] = (short)f2bf(W1[f]);
    }
    if (tid < NPAD) {
        b1s[tid] = (tid < 100) ? b1[tid] : 0.f;
        w2s[tid] = (tid < 100) ? W2[tid] : 0.f;
    }
    __syncthreads();

    const int lane = tid & 63;
    const int w    = tid >> 6;
    const int col  = lane & 15;
    const int quad = lane >> 4;
    const float b2v = b2[0];
    const int bid  = blockIdx.x - ZBLK;

    for (int grp = bid * 4 + w; grp < NGRP; grp += MBLK * 4) {
        int r  = grp * 16 + col;
        int rr = (r <= VOCAB_P1 - 1) ? r : (VOCAB_P1 - 1);
        const float* rp = emb + (size_t)rr * EMB_DIM + quad * 8;
        // A layout: A[m=lane&15][k=quad*8+j]  (m89/m91-verified)
        float4 u0 = *(const float4*)(rp);
        float4 u1 = *(const float4*)(rp + 4);
        float4 u2 = *(const float4*)(rp + 32);
        float4 u3 = *(const float4*)(rp + 36);
        float4 u4 = *(const float4*)(rp + 64);
        float4 u5 = *(const float4*)(rp + 68);
        float4 u6 = *(const float4*)(rp + 96);
        float4 u7 = *(const float4*)(rp + 100);
        short8 a0 = cvt8(u0, u1), a1 = cvt8(u2, u3);
        short8 a2 = cvt8(u4, u5), a3 = cvt8(u6, u7);

        float s0 = 0.f, s1 = 0.f, s2 = 0.f, s3 = 0.f;
        for (int jt = 0; jt < 7; ++jt) {
            const short* bp = &w1t[(jt * 16 + col) * ROWP + quad * 8];
            short8 bv0 = *(const short8*)(bp);
            short8 bv1 = *(const short8*)(bp + 32);
            short8 bv2 = *(const short8*)(bp + 64);
            short8 bv3 = *(const short8*)(bp + 96);

            float4v acc = {0.f, 0.f, 0.f, 0.f};
            acc = __builtin_amdgcn_mfma_f32_16x16x32_bf16(a0, bv0, acc, 0, 0, 0);
            acc = __builtin_amdgcn_mfma_f32_16x16x32_bf16(a1, bv1, acc, 0, 0, 0);
            acc = __builtin_amdgcn_mfma_f32_16x16x32_bf16(a2, bv2, acc, 0, 0, 0);
            acc = __builtin_amdgcn_mfma_f32_16x16x32_bf16(a3, bv3, acc, 0, 0, 0);

            // D layout: row = quad*4 + reg, col(j) = lane&15
            float b1v = b1s[jt * 16 + col];
            float w2v = w2s[jt * 16 + col];
            float h;
            h = acc[0] + b1v; h = h > 0.f ? h : 0.f; s0 += h * w2v;
            h = acc[1] + b1v; h = h > 0.f ? h : 0.f; s1 += h * w2v;
            h = acc[2] + b1v; h = h > 0.f ? h : 0.f; s2 += h * w2v;
            h = acc[3] + b1v; h = h > 0.f ? h : 0.f; s3 += h * w2v;
        }
        for (int m = 1; m < 16; m <<= 1) {
            s0 += __shfl_xor(s0, m, 64);
            s1 += __shfl_xor(s1, m, 64);
            s2 += __shfl_xor(s2, m, 64);
            s3 += __shfl_xor(s3, m, 64);
        }
        if (col < 4) {
            float sv = (col == 0) ? s0 : (col == 1) ? s1 : (col == 2) ? s2 : s3;
            int row = grp * 16 + quad * 4 + col;
            if (row < VOCAB_P1) {
                float tdv = sv + b2v;
                tdvtab[row] = tdv > 0.f ? tdv : 0.f;
            }
        }
    }
}

// Scatter: 1024 blocks x 1 entry/thread (16 waves/CU for gather/atomic
// latency hiding). LDS colsum per block; flushed to NCOPY=4 copies so each
// per-address global atomic chain is 256 deep (the depth R2/R4 showed fast).
__global__ __launch_bounds__(256) void scatter_kernel(
    const int* __restrict__ d_rows, const int* __restrict__ d_cols,
    const float* __restrict__ d_freqs, const float* __restrict__ tdvtab,
    float* __restrict__ dmat, float* __restrict__ colsum4)
{
    __shared__ float cs[BATCH];
    const int tid = threadIdx.x;
    cs[tid] = 0.f;
    __syncthreads();

    int e = blockIdx.x * 256 + tid;              // exactly covers NNZ_D
    int   r = d_rows[e];
    int   c = d_cols[e];
    float f = d_freqs[e];
    float ft = tdvtab[r] * f;

    atomicAdd(&dmat[(size_t)r * BATCH + c], ft);
    atomicAdd(&cs[c], ft);

    __syncthreads();
    atomicAdd(&colsum4[(blockIdx.x & (NCOPY - 1)) * BATCH + tid], cs[tid]);
}

// One WAVE per q-entry: rowsum[v] = sum of dmat row v (1 float4/lane),
// total = sum over colsum copies, both shuffle-reduced in-wave.
__global__ __launch_bounds__(256) void rel_kernel(
    const int* __restrict__ q_rows, const int* __restrict__ q_cols,
    const float* __restrict__ q_vals, const float* __restrict__ dmat,
    const float* __restrict__ colsum4, const float* __restrict__ mu_p,
    float* __restrict__ rel)
{
    const int tid  = threadIdx.x;
    const int lane = tid & 63;
    const int e    = blockIdx.x * 4 + (tid >> 6);   // 512 blocks x 4 waves

    int v = q_rows[e], b = q_cols[e];
    float qv = q_vals[e];
    float mu = mu_p[0];

    float tot_p = 0.f;
    for (int k = 0; k < NCOPY; ++k) {
        float4 cv = *(const float4*)(colsum4 + k * BATCH + lane * 4);
        tot_p += cv.x + cv.y + cv.z + cv.w;
    }
    float4 rv = *(const float4*)(dmat + (size_t)v * BATCH + lane * 4);
    float row_p = rv.x + rv.y + rv.z + rv.w;
    for (int m = 1; m < 64; m <<= 1) {
        tot_p += __shfl_xor(tot_p, m, 64);
        row_p += __shfl_xor(row_p, m, 64);
    }

    if (lane == 0) {
        float csb = 0.f;
        for (int k = 0; k < NCOPY; ++k) csb += colsum4[k * BATCH + b];
        float dval = dmat[(size_t)v * BATCH + b];
        float cf   = row_p / tot_p;
        float dir  = log1pf(dval / (1.f + mu * cf)) + logf(mu / (csb + mu));
        atomicAdd(&rel[b], qv * dir);
    }
}

extern "C" void kernel_launch(void* const* d_in, const int* in_sizes, int n_in,
                              void* d_out, int out_size, void* d_ws, size_t ws_size,
                              hipStream_t stream)
{
    const int*   q_rows  = (const int*)d_in[0];
    const int*   q_cols  = (const int*)d_in[1];
    const float* q_vals  = (const float*)d_in[2];
    const int*   d_rows  = (const int*)d_in[3];
    const int*   d_cols  = (const int*)d_in[4];
    const float* d_freqs = (const float*)d_in[5];
    const float* emb     = (const float*)d_in[6];
    const float* W1      = (const float*)d_in[7];
    const float* b1      = (const float*)d_in[8];
    const float* W2      = (const float*)d_in[9];
    const float* b2      = (const float*)d_in[10];
    const float* mu      = (const float*)d_in[11];

    float* rel  = (float*)d_out;            // output 0: rel [256]
    float* dmat = rel + BATCH;              // output 1: d [100001, 256]

    float* colsum4 = (float*)d_ws;          // [NCOPY][256]
    float* tdvtab  = colsum4 + NCOPY * BATCH;  // [100001]

    zero_mlp_kernel<<<ZBLK + MBLK, 256, 0, stream>>>(
        (float*)d_out, colsum4, emb, W1, b1, W2, b2, tdvtab);
    scatter_kernel<<<NNZ_D / 256, 256, 0, stream>>>(
        d_rows, d_cols, d_freqs, tdvtab, dmat, colsum4);
    rel_kernel<<<NNZ_Q / 4, 256, 0, stream>>>(
        q_rows, q_cols, q_vals, dmat, colsum4, mu, rel);
}

// Round 7
// 203.874 us; speedup vs baseline: 1.0170x; 1.0170x over previous
//
#include <hip/hip_runtime.h>
#include <stdint.h>

// Problem constants (fixed by the reference).
#define VOCAB_P1 100001
#define EMB_DIM  128
#define BATCH    256
#define NNZ_Q    2048
#define NNZ_D    262144

#define NPAD 112        // hidden dim 100 padded to 7 MFMA tiles of 16
#define ROWP 136        // w1t LDS row stride in shorts (128 + 8 pad)
#define NGRP 6251       // ceil(100001 / 16) row-groups
#define ZBLK 256        // zero-role blocks
#define MBLK 1024       // mlp-role blocks
#define NCOPY 2         // colsum copies: 512 scatter blocks / 2 = 256-deep chains
#define OUT_F4 6400128  // out_size/4 = 25,600,512 floats / 4

typedef __attribute__((ext_vector_type(8))) short  short8;
typedef __attribute__((ext_vector_type(4))) float  float4v;

__device__ __forceinline__ unsigned short f2bf(float f) {
    union { float f; unsigned u; } v; v.f = f;
    unsigned u = v.u;
    u += 0x7fffu + ((u >> 16) & 1u);     // RNE float -> bf16
    return (unsigned short)(u >> 16);
}

__device__ __forceinline__ short8 cvt8(float4 a, float4 b) {
    short8 r;
    r[0] = (short)f2bf(a.x); r[1] = (short)f2bf(a.y);
    r[2] = (short)f2bf(a.z); r[3] = (short)f2bf(a.w);
    r[4] = (short)f2bf(b.x); r[5] = (short)f2bf(b.y);
    r[6] = (short)f2bf(b.z); r[7] = (short)f2bf(b.w);
    return r;
}

// Block-role fused kernel (R4-verified):
//   blocks [0, ZBLK): zero d_out (rel + dmat) and the colsum copies.
//   blocks [ZBLK, ZBLK+MBLK): per-unique-row MLP tdv table.
__global__ __launch_bounds__(256) void zero_mlp_kernel(
    float* __restrict__ d_out_f, float* __restrict__ colsum2,
    const float* __restrict__ emb, const float* __restrict__ W1,
    const float* __restrict__ b1, const float* __restrict__ W2,
    const float* __restrict__ b2, float* __restrict__ tdvtab)
{
    const int tid = threadIdx.x;

    if (blockIdx.x < ZBLK) {
        const float4 z = {0.f, 0.f, 0.f, 0.f};
        float4* dst = (float4*)d_out_f;
        int i0 = blockIdx.x * 256 + tid;
        // 2x-unrolled streaming zero (OUT_F4 = 97.65 * 65536; handle tail).
        int i = i0;
        for (; i + ZBLK * 256 < OUT_F4; i += 2 * ZBLK * 256) {
            dst[i] = z;
            dst[i + ZBLK * 256] = z;
        }
        if (i < OUT_F4) dst[i] = z;
        if (i0 < NCOPY * BATCH / 4) ((float4*)colsum2)[i0] = z;
        return;
    }

    __shared__ __align__(16) short w1t[NPAD * ROWP];   // 30.5 KB
    __shared__ float b1s[NPAD];
    __shared__ float w2s[NPAD];

    int* w1i = (int*)w1t;
    for (int i = tid; i < NPAD * ROWP / 2; i += 256) w1i[i] = 0;
    __syncthreads();
    for (int f = tid; f < EMB_DIM * 100; f += 256) {
        int k = f / 100, j = f - k * 100;
        w1t[j * ROWP + k] = (short)f2bf(W1[f]);
    }
    if (tid < NPAD) {
        b1s[tid] = (tid < 100) ? b1[tid] : 0.f;
        w2s[tid] = (tid < 100) ? W2[tid] : 0.f;
    }
    __syncthreads();

    const int lane = tid & 63;
    const int w    = tid >> 6;
    const int col  = lane & 15;
    const int quad = lane >> 4;
    const float b2v = b2[0];
    const int bid  = blockIdx.x - ZBLK;

    for (int grp = bid * 4 + w; grp < NGRP; grp += MBLK * 4) {
        int r  = grp * 16 + col;
        int rr = (r <= VOCAB_P1 - 1) ? r : (VOCAB_P1 - 1);
        const float* rp = emb + (size_t)rr * EMB_DIM + quad * 8;
        // A layout: A[m=lane&15][k=quad*8+j]  (m89/m91-verified)
        float4 u0 = *(const float4*)(rp);
        float4 u1 = *(const float4*)(rp + 4);
        float4 u2 = *(const float4*)(rp + 32);
        float4 u3 = *(const float4*)(rp + 36);
        float4 u4 = *(const float4*)(rp + 64);
        float4 u5 = *(const float4*)(rp + 68);
        float4 u6 = *(const float4*)(rp + 96);
        float4 u7 = *(const float4*)(rp + 100);
        short8 a0 = cvt8(u0, u1), a1 = cvt8(u2, u3);
        short8 a2 = cvt8(u4, u5), a3 = cvt8(u6, u7);

        float s0 = 0.f, s1 = 0.f, s2 = 0.f, s3 = 0.f;
        for (int jt = 0; jt < 7; ++jt) {
            const short* bp = &w1t[(jt * 16 + col) * ROWP + quad * 8];
            short8 bv0 = *(const short8*)(bp);
            short8 bv1 = *(const short8*)(bp + 32);
            short8 bv2 = *(const short8*)(bp + 64);
            short8 bv3 = *(const short8*)(bp + 96);

            float4v acc = {0.f, 0.f, 0.f, 0.f};
            acc = __builtin_amdgcn_mfma_f32_16x16x32_bf16(a0, bv0, acc, 0, 0, 0);
            acc = __builtin_amdgcn_mfma_f32_16x16x32_bf16(a1, bv1, acc, 0, 0, 0);
            acc = __builtin_amdgcn_mfma_f32_16x16x32_bf16(a2, bv2, acc, 0, 0, 0);
            acc = __builtin_amdgcn_mfma_f32_16x16x32_bf16(a3, bv3, acc, 0, 0, 0);

            // D layout: row = quad*4 + reg, col(j) = lane&15
            float b1v = b1s[jt * 16 + col];
            float w2v = w2s[jt * 16 + col];
            float h;
            h = acc[0] + b1v; h = h > 0.f ? h : 0.f; s0 += h * w2v;
            h = acc[1] + b1v; h = h > 0.f ? h : 0.f; s1 += h * w2v;
            h = acc[2] + b1v; h = h > 0.f ? h : 0.f; s2 += h * w2v;
            h = acc[3] + b1v; h = h > 0.f ? h : 0.f; s3 += h * w2v;
        }
        for (int m = 1; m < 16; m <<= 1) {
            s0 += __shfl_xor(s0, m, 64);
            s1 += __shfl_xor(s1, m, 64);
            s2 += __shfl_xor(s2, m, 64);
            s3 += __shfl_xor(s3, m, 64);
        }
        if (col < 4) {
            float sv = (col == 0) ? s0 : (col == 1) ? s1 : (col == 2) ? s2 : s3;
            int row = grp * 16 + quad * 4 + col;
            if (row < VOCAB_P1) {
                float tdv = sv + b2v;
                tdvtab[row] = tdv > 0.f ? tdv : 0.f;
            }
        }
    }
}

// Scatter (R4-measured best): 512 blocks x 2 entries/thread (8 waves/CU).
// LDS colsum per block; flushed to NCOPY=2 copies by block parity
// (131K flush atomics, 256-deep per-address chains).
__global__ __launch_bounds__(256) void scatter_kernel(
    const int* __restrict__ d_rows, const int* __restrict__ d_cols,
    const float* __restrict__ d_freqs, const float* __restrict__ tdvtab,
    float* __restrict__ dmat, float* __restrict__ colsum2)
{
    __shared__ float cs[BATCH];
    const int tid = threadIdx.x;
    cs[tid] = 0.f;
    __syncthreads();

    int g = blockIdx.x * 256 + tid;              // int2 index, 131072 total
    int2   r2 = ((const int2*)d_rows)[g];
    int2   c2 = ((const int2*)d_cols)[g];
    float2 f2 = ((const float2*)d_freqs)[g];

    float ft0 = tdvtab[r2.x] * f2.x;
    float ft1 = tdvtab[r2.y] * f2.y;

    atomicAdd(&dmat[(size_t)r2.x * BATCH + c2.x], ft0);
    atomicAdd(&dmat[(size_t)r2.y * BATCH + c2.y], ft1);
    atomicAdd(&cs[c2.x], ft0);
    atomicAdd(&cs[c2.y], ft1);

    __syncthreads();
    atomicAdd(&colsum2[(blockIdx.x & (NCOPY - 1)) * BATCH + tid], cs[tid]);
}

// One WAVE per q-entry: rowsum[v] = sum of dmat row v (1 float4/lane),
// total = sum over colsum copies, both shuffle-reduced in-wave.
__global__ __launch_bounds__(256) void rel_kernel(
    const int* __restrict__ q_rows, const int* __restrict__ q_cols,
    const float* __restrict__ q_vals, const float* __restrict__ dmat,
    const float* __restrict__ colsum2, const float* __restrict__ mu_p,
    float* __restrict__ rel)
{
    const int tid  = threadIdx.x;
    const int lane = tid & 63;
    const int e    = blockIdx.x * 4 + (tid >> 6);   // 512 blocks x 4 waves

    int v = q_rows[e], b = q_cols[e];
    float qv = q_vals[e];
    float mu = mu_p[0];

    float tot_p = 0.f;
    for (int k = 0; k < NCOPY; ++k) {
        float4 cv = *(const float4*)(colsum2 + k * BATCH + lane * 4);
        tot_p += cv.x + cv.y + cv.z + cv.w;
    }
    float4 rv = *(const float4*)(dmat + (size_t)v * BATCH + lane * 4);
    float row_p = rv.x + rv.y + rv.z + rv.w;
    for (int m = 1; m < 64; m <<= 1) {
        tot_p += __shfl_xor(tot_p, m, 64);
        row_p += __shfl_xor(row_p, m, 64);
    }

    if (lane == 0) {
        float csb = 0.f;
        for (int k = 0; k < NCOPY; ++k) csb += colsum2[k * BATCH + b];
        float dval = dmat[(size_t)v * BATCH + b];
        float cf   = row_p / tot_p;
        float dir  = log1pf(dval / (1.f + mu * cf)) + logf(mu / (csb + mu));
        atomicAdd(&rel[b], qv * dir);
    }
}

extern "C" void kernel_launch(void* const* d_in, const int* in_sizes, int n_in,
                              void* d_out, int out_size, void* d_ws, size_t ws_size,
                              hipStream_t stream)
{
    const int*   q_rows  = (const int*)d_in[0];
    const int*   q_cols  = (const int*)d_in[1];
    const float* q_vals  = (const float*)d_in[2];
    const int*   d_rows  = (const int*)d_in[3];
    const int*   d_cols  = (const int*)d_in[4];
    const float* d_freqs = (const float*)d_in[5];
    const float* emb     = (const float*)d_in[6];
    const float* W1      = (const float*)d_in[7];
    const float* b1      = (const float*)d_in[8];
    const float* W2      = (const float*)d_in[9];
    const float* b2      = (const float*)d_in[10];
    const float* mu      = (const float*)d_in[11];

    float* rel  = (float*)d_out;            // output 0: rel [256]
    float* dmat = rel + BATCH;              // output 1: d [100001, 256]

    float* colsum2 = (float*)d_ws;          // [NCOPY][256]
    float* tdvtab  = colsum2 + NCOPY * BATCH;  // [100001]

    zero_mlp_kernel<<<ZBLK + MBLK, 256, 0, stream>>>(
        (float*)d_out, colsum2, emb, W1, b1, W2, b2, tdvtab);
    scatter_kernel<<<NNZ_D / 512, 256, 0, stream>>>(
        d_rows, d_cols, d_freqs, tdvtab, dmat, colsum2);
    rel_kernel<<<NNZ_Q / 4, 256, 0, stream>>>(
        q_rows, q_cols, q_vals, dmat, colsum2, mu, rel);
}

// Round 8
// 201.616 us; speedup vs baseline: 1.0283x; 1.0112x over previous
//
#include <hip/hip_runtime.h>
#include <stdint.h>

// Problem constants (fixed by the reference).
#define VOCAB_P1 100001
#define EMB_DIM  128
#define BATCH    256
#define NNZ_Q    2048
#define NNZ_D    262144

#define NPAD 112        // hidden dim 100 padded to 7 MFMA tiles of 16
#define ROWP 136        // w1t LDS row stride in shorts (128 + 8 pad)
#define NGRP 6251       // ceil(100001 / 16) row-groups
#define ZBLK 256        // zero-role blocks
#define MBLK 1563       // mlp-role blocks: 1563*4 = 6252 waves = 1 group/wave
#define NCOPY 2         // colsum copies: 512 scatter blocks / 2 = 256-deep chains
#define OUT_F4 6400128  // out_size/4 = 25,600,512 floats / 4

typedef __attribute__((ext_vector_type(8))) short  short8;
typedef __attribute__((ext_vector_type(4))) float  float4v;

__device__ __forceinline__ unsigned short f2bf(float f) {
    union { float f; unsigned u; } v; v.f = f;
    unsigned u = v.u;
    u += 0x7fffu + ((u >> 16) & 1u);     // RNE float -> bf16
    return (unsigned short)(u >> 16);
}

__device__ __forceinline__ short8 cvt8(float4 a, float4 b) {
    short8 r;
    r[0] = (short)f2bf(a.x); r[1] = (short)f2bf(a.y);
    r[2] = (short)f2bf(a.z); r[3] = (short)f2bf(a.w);
    r[4] = (short)f2bf(b.x); r[5] = (short)f2bf(b.y);
    r[6] = (short)f2bf(b.z); r[7] = (short)f2bf(b.w);
    return r;
}

// Block-role fused kernel:
//   blocks [0, ZBLK): zero d_out (rel + dmat) and the colsum copies.
//   blocks [ZBLK, ZBLK+MBLK): per-unique-row MLP tdv table, exactly ONE
//   16-row group per wave (balanced; no 2-group tail).
__global__ __launch_bounds__(256) void zero_mlp_kernel(
    float* __restrict__ d_out_f, float* __restrict__ colsum2,
    const float* __restrict__ emb, const float* __restrict__ W1,
    const float* __restrict__ b1, const float* __restrict__ W2,
    const float* __restrict__ b2, float* __restrict__ tdvtab)
{
    const int tid = threadIdx.x;

    if (blockIdx.x < ZBLK) {
        const float4 z = {0.f, 0.f, 0.f, 0.f};
        float4* dst = (float4*)d_out_f;
        int i0 = blockIdx.x * 256 + tid;
        int i = i0;
        for (; i + ZBLK * 256 < OUT_F4; i += 2 * ZBLK * 256) {
            dst[i] = z;
            dst[i + ZBLK * 256] = z;
        }
        if (i < OUT_F4) dst[i] = z;
        if (i0 < NCOPY * BATCH / 4) ((float4*)colsum2)[i0] = z;
        return;
    }

    __shared__ __align__(16) short w1t[NPAD * ROWP];   // 30.5 KB
    __shared__ float b1s[NPAD];
    __shared__ float w2s[NPAD];

    int* w1i = (int*)w1t;
    for (int i = tid; i < NPAD * ROWP / 2; i += 256) w1i[i] = 0;
    __syncthreads();
    for (int f = tid; f < EMB_DIM * 100; f += 256) {
        int k = f / 100, j = f - k * 100;
        w1t[j * ROWP + k] = (short)f2bf(W1[f]);
    }
    if (tid < NPAD) {
        b1s[tid] = (tid < 100) ? b1[tid] : 0.f;
        w2s[tid] = (tid < 100) ? W2[tid] : 0.f;
    }
    __syncthreads();

    const int lane = tid & 63;
    const int w    = tid >> 6;
    const int col  = lane & 15;
    const int quad = lane >> 4;
    const float b2v = b2[0];

    const int grp = (blockIdx.x - ZBLK) * 4 + w;   // one group per wave
    if (grp >= NGRP) return;

    int r  = grp * 16 + col;
    int rr = (r <= VOCAB_P1 - 1) ? r : (VOCAB_P1 - 1);
    const float* rp = emb + (size_t)rr * EMB_DIM + quad * 8;
    // A layout: A[m=lane&15][k=quad*8+j]  (m89/m91-verified)
    float4 u0 = *(const float4*)(rp);
    float4 u1 = *(const float4*)(rp + 4);
    float4 u2 = *(const float4*)(rp + 32);
    float4 u3 = *(const float4*)(rp + 36);
    float4 u4 = *(const float4*)(rp + 64);
    float4 u5 = *(const float4*)(rp + 68);
    float4 u6 = *(const float4*)(rp + 96);
    float4 u7 = *(const float4*)(rp + 100);
    short8 a0 = cvt8(u0, u1), a1 = cvt8(u2, u3);
    short8 a2 = cvt8(u4, u5), a3 = cvt8(u6, u7);

    float s0 = 0.f, s1 = 0.f, s2 = 0.f, s3 = 0.f;
    for (int jt = 0; jt < 7; ++jt) {
        const short* bp = &w1t[(jt * 16 + col) * ROWP + quad * 8];
        short8 bv0 = *(const short8*)(bp);
        short8 bv1 = *(const short8*)(bp + 32);
        short8 bv2 = *(const short8*)(bp + 64);
        short8 bv3 = *(const short8*)(bp + 96);

        float4v acc = {0.f, 0.f, 0.f, 0.f};
        acc = __builtin_amdgcn_mfma_f32_16x16x32_bf16(a0, bv0, acc, 0, 0, 0);
        acc = __builtin_amdgcn_mfma_f32_16x16x32_bf16(a1, bv1, acc, 0, 0, 0);
        acc = __builtin_amdgcn_mfma_f32_16x16x32_bf16(a2, bv2, acc, 0, 0, 0);
        acc = __builtin_amdgcn_mfma_f32_16x16x32_bf16(a3, bv3, acc, 0, 0, 0);

        // D layout: row = quad*4 + reg, col(j) = lane&15
        float b1v = b1s[jt * 16 + col];
        float w2v = w2s[jt * 16 + col];
        float h;
        h = acc[0] + b1v; h = h > 0.f ? h : 0.f; s0 += h * w2v;
        h = acc[1] + b1v; h = h > 0.f ? h : 0.f; s1 += h * w2v;
        h = acc[2] + b1v; h = h > 0.f ? h : 0.f; s2 += h * w2v;
        h = acc[3] + b1v; h = h > 0.f ? h : 0.f; s3 += h * w2v;
    }
    for (int m = 1; m < 16; m <<= 1) {
        s0 += __shfl_xor(s0, m, 64);
        s1 += __shfl_xor(s1, m, 64);
        s2 += __shfl_xor(s2, m, 64);
        s3 += __shfl_xor(s3, m, 64);
    }
    if (col < 4) {
        float sv = (col == 0) ? s0 : (col == 1) ? s1 : (col == 2) ? s2 : s3;
        int row = grp * 16 + quad * 4 + col;
        if (row < VOCAB_P1) {
            float tdv = sv + b2v;
            tdvtab[row] = tdv > 0.f ? tdv : 0.f;
        }
    }
}

// Scatter (R4-measured best): 512 blocks x 2 entries/thread (8 waves/CU).
// LDS colsum per block; flushed to NCOPY=2 copies by block parity.
__global__ __launch_bounds__(256) void scatter_kernel(
    const int* __restrict__ d_rows, const int* __restrict__ d_cols,
    const float* __restrict__ d_freqs, const float* __restrict__ tdvtab,
    float* __restrict__ dmat, float* __restrict__ colsum2)
{
    __shared__ float cs[BATCH];
    const int tid = threadIdx.x;
    cs[tid] = 0.f;
    __syncthreads();

    int g = blockIdx.x * 256 + tid;              // int2 index, 131072 total
    int2   r2 = ((const int2*)d_rows)[g];
    int2   c2 = ((const int2*)d_cols)[g];
    float2 f2 = ((const float2*)d_freqs)[g];

    float ft0 = tdvtab[r2.x] * f2.x;
    float ft1 = tdvtab[r2.y] * f2.y;

    atomicAdd(&dmat[(size_t)r2.x * BATCH + c2.x], ft0);
    atomicAdd(&dmat[(size_t)r2.y * BATCH + c2.y], ft1);
    atomicAdd(&cs[c2.x], ft0);
    atomicAdd(&cs[c2.y], ft1);

    __syncthreads();
    atomicAdd(&colsum2[(blockIdx.x & (NCOPY - 1)) * BATCH + tid], cs[tid]);
}

// One WAVE per q-entry: rowsum[v] = sum of dmat row v (1 float4/lane),
// total = sum over colsum copies, both shuffle-reduced in-wave.
__global__ __launch_bounds__(256) void rel_kernel(
    const int* __restrict__ q_rows, const int* __restrict__ q_cols,
    const float* __restrict__ q_vals, const float* __restrict__ dmat,
    const float* __restrict__ colsum2, const float* __restrict__ mu_p,
    float* __restrict__ rel)
{
    const int tid  = threadIdx.x;
    const int lane = tid & 63;
    const int e    = blockIdx.x * 4 + (tid >> 6);   // 512 blocks x 4 waves

    int v = q_rows[e], b = q_cols[e];
    float qv = q_vals[e];
    float mu = mu_p[0];

    float tot_p = 0.f;
    for (int k = 0; k < NCOPY; ++k) {
        float4 cv = *(const float4*)(colsum2 + k * BATCH + lane * 4);
        tot_p += cv.x + cv.y + cv.z + cv.w;
    }
    float4 rv = *(const float4*)(dmat + (size_t)v * BATCH + lane * 4);
    float row_p = rv.x + rv.y + rv.z + rv.w;
    for (int m = 1; m < 64; m <<= 1) {
        tot_p += __shfl_xor(tot_p, m, 64);
        row_p += __shfl_xor(row_p, m, 64);
    }

    if (lane == 0) {
        float csb = 0.f;
        for (int k = 0; k < NCOPY; ++k) csb += colsum2[k * BATCH + b];
        float dval = dmat[(size_t)v * BATCH + b];
        float cf   = row_p / tot_p;
        float dir  = log1pf(dval / (1.f + mu * cf)) + logf(mu / (csb + mu));
        atomicAdd(&rel[b], qv * dir);
    }
}

extern "C" void kernel_launch(void* const* d_in, const int* in_sizes, int n_in,
                              void* d_out, int out_size, void* d_ws, size_t ws_size,
                              hipStream_t stream)
{
    const int*   q_rows  = (const int*)d_in[0];
    const int*   q_cols  = (const int*)d_in[1];
    const float* q_vals  = (const float*)d_in[2];
    const int*   d_rows  = (const int*)d_in[3];
    const int*   d_cols  = (const int*)d_in[4];
    const float* d_freqs = (const float*)d_in[5];
    const float* emb     = (const float*)d_in[6];
    const float* W1      = (const float*)d_in[7];
    const float* b1      = (const float*)d_in[8];
    const float* W2      = (const float*)d_in[9];
    const float* b2      = (const float*)d_in[10];
    const float* mu      = (const float*)d_in[11];

    float* rel  = (float*)d_out;            // output 0: rel [256]
    float* dmat = rel + BATCH;              // output 1: d [100001, 256]

    float* colsum2 = (float*)d_ws;          // [NCOPY][256]
    float* tdvtab  = colsum2 + NCOPY * BATCH;  // [100001]

    zero_mlp_kernel<<<ZBLK + MBLK, 256, 0, stream>>>(
        (float*)d_out, colsum2, emb, W1, b1, W2, b2, tdvtab);
    scatter_kernel<<<NNZ_D / 512, 256, 0, stream>>>(
        d_rows, d_cols, d_freqs, tdvtab, dmat, colsum2);
    rel_kernel<<<NNZ_Q / 4, 256, 0, stream>>>(
        q_rows, q_cols, q_vals, dmat, colsum2, mu, rel);
}